// Round 5
// baseline (116.481 us; speedup 1.0000x reference)
//
#include <hip/hip_runtime.h>
#include <hip/hip_bf16.h>

#define HW 3136
#define W56 56

typedef __attribute__((ext_vector_type(8))) short short8;
typedef __attribute__((ext_vector_type(4))) float f32x4;

static __device__ __forceinline__ f32x4 mfma16(short8 a, short8 b, f32x4 c) {
    return __builtin_amdgcn_mfma_f32_16x16x32_bf16(a, b, c, 0, 0, 0);
}
static __device__ __forceinline__ float b2f(unsigned short u) {
    unsigned int x = ((unsigned int)u) << 16;
    return __builtin_bit_cast(float, x);
}
static __device__ __forceinline__ unsigned short f2b(float f) {
    __hip_bfloat16 h = __float2bfloat16(f);
    return *(unsigned short*)&h;
}

// ---------------- prep ----------------
// blocks 0..3135: transpose x -> catb bf16 cols 0..255 (hi) + xlo bf16 [4HW][256]
// blocks 3136..3647: weight conversion (Wqk split hi/lo, Wv plain bf16)
__global__ __launch_bounds__(256) void prep(const float* __restrict__ x,
                                            const float* __restrict__ Wq, const float* __restrict__ Wk,
                                            const float* __restrict__ Wv,
                                            unsigned short* __restrict__ catb,
                                            unsigned short* __restrict__ xlo,
                                            unsigned short* __restrict__ Wqk_hi,
                                            unsigned short* __restrict__ Wqk_lo,
                                            unsigned short* __restrict__ Wvb) {
    __shared__ float tile[32][33];
    int bx = blockIdx.x, tid = threadIdx.x;
    if (bx < 3136) {
        int b = bx / 784, rem = bx % 784;
        int p0 = (rem >> 3) * 32, c0 = (rem & 7) * 32;
        int tx = tid & 31, ty = tid >> 5;
#pragma unroll
        for (int i = ty; i < 32; i += 8)
            tile[i][tx] = x[((size_t)b * 256 + c0 + i) * HW + p0 + tx];
        __syncthreads();
#pragma unroll
        for (int i = ty; i < 32; i += 8) {
            float v = tile[tx][i];
            unsigned short hi = f2b(v);
            unsigned short lo = f2b(v - b2f(hi));
            size_t row = (size_t)b * HW + p0 + i;
            catb[row * 512 + c0 + tx] = hi;
            xlo[row * 256 + c0 + tx] = lo;
        }
    } else {
        int i = (bx - 3136) * 256 + tid;
        if (i < 32768) {
            float w = (i < 16384) ? Wq[i] : Wk[i - 16384];
            unsigned short hi = f2b(w);
            Wqk_hi[i] = hi;
            Wqk_lo[i] = f2b(w - b2f(hi));
        }
        if (i < 131072) Wvb[i] = f2b(Wv[i]);
    }
}

// ---------------- projqk: 64 W-rows x px(32), K=256, split-bf16 (3 MFMA products) ----------------
// grid.x = npx/32, grid.y = 2 (y=0 -> Q rows 0..63, y=1 -> K rows 64..127).
__global__ __launch_bounds__(256) void projqk(const unsigned short* __restrict__ Whi,
                                              const unsigned short* __restrict__ Wlo,
                                              const unsigned short* __restrict__ Bhi_g, int bstr,
                                              const unsigned short* __restrict__ Blo_g,
                                              float* __restrict__ Qout, float* __restrict__ Kout) {
    __shared__ short Ahi[64][72], Alo[64][72];
    __shared__ short Bhi[32][72], Blo[32][72];
    int tid = threadIdx.x, lane = tid & 63, wv = tid >> 6;
    int l15 = lane & 15, lk = (lane >> 4) * 8;
    int pxb = blockIdx.x * 32;
    int y64 = blockIdx.y * 64;
    f32x4 acc[2];
    acc[0] = (f32x4){0.f, 0.f, 0.f, 0.f};
    acc[1] = (f32x4){0.f, 0.f, 0.f, 0.f};

    for (int kt = 0; kt < 256; kt += 64) {
#pragma unroll
        for (int s = 0; s < 2; ++s) {
            int q = tid + 256 * s;
            int r = q >> 3, c = (q & 7) * 8;
            *(short8*)&Ahi[r][c] = *(const short8*)(Whi + (size_t)(y64 + r) * 256 + kt + c);
            *(short8*)&Alo[r][c] = *(const short8*)(Wlo + (size_t)(y64 + r) * 256 + kt + c);
        }
        {
            int r = tid >> 3, c = (tid & 7) * 8;
            *(short8*)&Bhi[r][c] = *(const short8*)(Bhi_g + (size_t)(pxb + r) * bstr + kt + c);
            *(short8*)&Blo[r][c] = *(const short8*)(Blo_g + (size_t)(pxb + r) * 256 + kt + c);
        }
        __syncthreads();
#pragma unroll
        for (int ks = 0; ks < 2; ++ks) {
            short8 ah = *(const short8*)&Ahi[wv * 16 + l15][ks * 32 + lk];
            short8 al = *(const short8*)&Alo[wv * 16 + l15][ks * 32 + lk];
            short8 bh[2], bl[2];
#pragma unroll
            for (int j = 0; j < 2; ++j) {
                bh[j] = *(const short8*)&Bhi[j * 16 + l15][ks * 32 + lk];
                bl[j] = *(const short8*)&Blo[j * 16 + l15][ks * 32 + lk];
            }
#pragma unroll
            for (int j = 0; j < 2; ++j) {
                acc[j] = mfma16(ah, bh[j], acc[j]);
                acc[j] = mfma16(ah, bl[j], acc[j]);
                acc[j] = mfma16(al, bh[j], acc[j]);
            }
        }
        __syncthreads();
    }
    int d0 = wv * 16 + (lane >> 4) * 4;
    float* base = blockIdx.y ? Kout : Qout;
#pragma unroll
    for (int j = 0; j < 2; ++j) {
        int px = pxb + j * 16 + l15;
        *(f32x4*)(base + (size_t)px * 64 + d0) = acc[j];
    }
}

// ---------------- attention: block = 4 consecutive pixels of one image row ----------------
// Stages the 7x10 neighborhood UNION of V (bf16 [70][256]) and K (f32 [70][68] padded) in LDS:
// cuts L2 gather traffic ~2.8x (4 waves share the union). Invalid slots zero-filled (w=0 there).
// DOQK: emit Qn/Kn of the attention output via linearity (Q gather from L2, Kn from staged K).
template <bool DOQK>
__global__ __launch_bounds__(256) void attn_kernel(const float* __restrict__ Q, const float* __restrict__ Kself,
                                                   const float* __restrict__ Kb,
                                                   const unsigned short* __restrict__ V,
                                                   unsigned short* __restrict__ outb,
                                                   const float* __restrict__ Qlin,
                                                   float* __restrict__ Qnout, float* __restrict__ Knout) {
    __shared__ unsigned short Vs[70 * 256];   // 35840 B
    __shared__ float Ks[70 * 68];             // 19040 B (stride 68 spreads banks: slot*68%32 = 4*(slot%8))
    __shared__ float qs[4][64];
    __shared__ float wsh[4][64];
    __shared__ int slotsh[4][64];
    __shared__ int njsh[4][64];
    int tid = threadIdx.x, lane = tid & 63, wv = tid >> 6;
    int lb = blockIdx.x;
    int q4 = lb % 14, row = (lb / 14) % 56, b = lb / 784;
    int px0 = q4 * 4;
    int pix = row * W56 + px0 + wv;
    int gw = b * HW + pix;

    qs[wv][lane] = Q[(size_t)gw * 64 + lane];

    const unsigned short* Vb = V + (size_t)b * HW * 512;
    const float* Kbb = Kb + (size_t)b * HW * 64;
    // stage V union: 70 slots x 64 ushort4-quads = 4480 items
#pragma unroll
    for (int it = 0; it < 18; ++it) {
        int item = it * 256 + tid;
        if (item < 4480) {
            int slot = item >> 6, qd = item & 63;
            int r = slot / 10, c = slot % 10;
            int ny = row - 3 + r, nx = px0 - 3 + c;
            ushort4 val = make_ushort4(0, 0, 0, 0);
            if (ny >= 0 && ny < W56 && nx >= 0 && nx < W56)
                val = *(const ushort4*)(Vb + ((size_t)(ny * W56 + nx)) * 512 + qd * 4);
            *(ushort4*)&Vs[slot * 256 + qd * 4] = val;
        }
    }
    // stage K union: 70 slots x 16 float4s = 1120 items
#pragma unroll
    for (int it = 0; it < 5; ++it) {
        int item = it * 256 + tid;
        if (item < 1120) {
            int slot = item >> 4, f4 = item & 15;
            int r = slot / 10, c = slot % 10;
            int ny = row - 3 + r, nx = px0 - 3 + c;
            float4 val = make_float4(0.f, 0.f, 0.f, 0.f);
            if (ny >= 0 && ny < W56 && nx >= 0 && nx < W56)
                val = *(const float4*)(Kbb + ((size_t)(ny * W56 + nx)) * 64 + f4 * 4);
            *(float4*)&Ks[slot * 68 + f4 * 4] = val;
        }
    }
    __syncthreads();

    int py = row, px = px0 + wv;
    float logit = 0.f;
    int valid = 0, nj = 0, slot = 0;
    if (lane == 0) {
        valid = 1;
    } else if (lane < 50) {
        int d = lane - 1, dy = d / 7 - 3, dx = d % 7 - 3;
        int ny = py + dy, nx = px + dx;
        if (ny >= 0 && ny < W56 && nx >= 0 && nx < W56) {
            valid = 1;
            nj = ny * W56 + nx;
            slot = (dy + 3) * 10 + (wv + dx + 3);
        }
    }
    if (lane < 50 && valid) {
        const float4* q4v = (const float4*)qs[wv];
        float acc = 0.f;
        if (lane == 0) {
            const float4* k4 = (const float4*)(Kself + (size_t)gw * 64);
#pragma unroll
            for (int i = 0; i < 16; ++i) {
                float4 kv = k4[i], qv = q4v[i];
                acc += kv.x * qv.x + kv.y * qv.y + kv.z * qv.z + kv.w * qv.w;
            }
        } else {
            const float4* k4 = (const float4*)&Ks[slot * 68];
#pragma unroll
            for (int i = 0; i < 16; ++i) {
                float4 kv = k4[i], qv = q4v[i];
                acc += kv.x * qv.x + kv.y * qv.y + kv.z * qv.z + kv.w * qv.w;
            }
        }
        logit = acc;
    }
    // zero-padded (OOB) neighbors: logit exactly 0, in denominator (matches reference)
    float m = (lane < 50) ? logit : -1e30f;
#pragma unroll
    for (int off = 32; off; off >>= 1) m = fmaxf(m, __shfl_xor(m, off));
    float e = (lane < 50) ? __expf(logit - m) : 0.f;
    float s = e;
#pragma unroll
    for (int off = 32; off; off >>= 1) s += __shfl_xor(s, off);
    // self column (lane 0) dropped; OOB & pad lanes weight 0, slot/nj 0 -> branchless loops exact
    float w = (lane >= 1 && lane < 50 && valid) ? e / s : 0.f;
    wsh[wv][lane] = w;
    slotsh[wv][lane] = slot;
    njsh[wv][lane] = nj;
    __syncthreads();

    float4 acc = make_float4(0.f, 0.f, 0.f, 0.f);
    float qacc = 0.f, kacc = 0.f;
    const float* qb = Qlin + (size_t)b * HW * 64 + lane;
#pragma unroll
    for (int g = 0; g < 7; ++g) {
        float wj[8];
        ushort4 vj[8];
        float qj[8], kj[8];
#pragma unroll
        for (int u = 0; u < 8; ++u) {
            int j = g * 8 + u;
            int sl = slotsh[wv][j];
            wj[u] = wsh[wv][j];
            vj[u] = *(const ushort4*)&Vs[sl * 256 + lane * 4];
            if (DOQK) {
                qj[u] = qb[(size_t)njsh[wv][j] * 64];
                kj[u] = Ks[sl * 68 + lane];
            }
        }
#pragma unroll
        for (int u = 0; u < 8; ++u) {
            acc.x += wj[u] * b2f(vj[u].x);
            acc.y += wj[u] * b2f(vj[u].y);
            acc.z += wj[u] * b2f(vj[u].z);
            acc.w += wj[u] * b2f(vj[u].w);
            if (DOQK) {
                qacc += wj[u] * qj[u];
                kacc += wj[u] * kj[u];
            }
        }
    }
    ushort4 pk;
    pk.x = f2b(acc.x); pk.y = f2b(acc.y); pk.z = f2b(acc.z); pk.w = f2b(acc.w);
    *(ushort4*)(outb + (size_t)gw * 512 + lane * 4) = pk;
    if (DOQK) {
        Qnout[(size_t)gw * 64 + lane] = qacc;
        Knout[(size_t)gw * 64 + lane] = kacc;
    }
}

// ---------------- conv (512->256) via MFMA + BN + ReLU ----------------
__global__ __launch_bounds__(256) void conv_mfma(const unsigned short* __restrict__ catb,
                                                 const unsigned short* __restrict__ Wvb,
                                                 const float* __restrict__ bv, const float* __restrict__ gamma,
                                                 const float* __restrict__ beta, const float* __restrict__ rmean,
                                                 const float* __restrict__ rvar, float* __restrict__ out) {
    __shared__ short Ald[64][72];
    __shared__ short Bld[64][72];
    int tid = threadIdx.x, lane = tid & 63, wv = tid >> 6;
    int wm = wv >> 1, wn = wv & 1;
    int l15 = lane & 15, lk = (lane >> 4) * 8;
    int n0g = blockIdx.x * 64;
    int m0g = blockIdx.y * 64;
    f32x4 acc[2][2];
#pragma unroll
    for (int i = 0; i < 2; ++i)
#pragma unroll
        for (int j = 0; j < 2; ++j) acc[i][j] = (f32x4){0.f, 0.f, 0.f, 0.f};

    float sc_[2][4], sh_[2][4];
#pragma unroll
    for (int i = 0; i < 2; ++i) {
        int ob = m0g + wm * 32 + i * 16 + (lane >> 4) * 4;
#pragma unroll
        for (int r = 0; r < 4; ++r) {
            int o = ob + r;
            float s = gamma[o] * rsqrtf(rvar[o] + 1e-5f);
            sc_[i][r] = s;
            sh_[i][r] = (bv[o] - rmean[o]) * s + beta[o];
        }
    }

    for (int kt = 0; kt < 512; kt += 64) {
#pragma unroll
        for (int s = 0; s < 2; ++s) {
            int q = tid + 256 * s;
            int r = q >> 3, c = (q & 7) * 8;
            *(short8*)&Ald[r][c] = *(const short8*)(Wvb + (size_t)(m0g + r) * 512 + kt + c);
            *(short8*)&Bld[r][c] = *(const short8*)(catb + (size_t)(n0g + r) * 512 + kt + c);
        }
        __syncthreads();
#pragma unroll
        for (int ks = 0; ks < 2; ++ks) {
            short8 a[2], b[2];
#pragma unroll
            for (int i = 0; i < 2; ++i) a[i] = *(const short8*)&Ald[wm * 32 + i * 16 + l15][ks * 32 + lk];
#pragma unroll
            for (int j = 0; j < 2; ++j) b[j] = *(const short8*)&Bld[wn * 32 + j * 16 + l15][ks * 32 + lk];
#pragma unroll
            for (int i = 0; i < 2; ++i)
#pragma unroll
                for (int j = 0; j < 2; ++j) acc[i][j] = mfma16(a[i], b[j], acc[i][j]);
        }
        __syncthreads();
    }
#pragma unroll
    for (int i = 0; i < 2; ++i) {
        int ob = m0g + wm * 32 + i * 16 + (lane >> 4) * 4;
#pragma unroll
        for (int j = 0; j < 2; ++j) {
            int px = n0g + wn * 32 + j * 16 + l15;
            int b = px / HW, p = px - b * HW;
            f32x4 v = acc[i][j];
#pragma unroll
            for (int r = 0; r < 4; ++r) {
                out[((size_t)(b * 256 + ob + r)) * HW + p] = fmaxf(v[r] * sc_[i][r] + sh_[i][r], 0.f);
            }
        }
    }
}

extern "C" void kernel_launch(void* const* d_in, const int* in_sizes, int n_in,
                              void* d_out, int out_size, void* d_ws, size_t ws_size,
                              hipStream_t stream) {
    const float* x     = (const float*)d_in[0];
    const float* Wq    = (const float*)d_in[1];
    const float* Wk    = (const float*)d_in[2];
    const float* Wv    = (const float*)d_in[3];
    const float* bv    = (const float*)d_in[4];
    const float* gamma = (const float*)d_in[5];
    const float* beta  = (const float*)d_in[6];
    const float* rmean = (const float*)d_in[7];
    const float* rvar  = (const float*)d_in[8];
    float* out = (float*)d_out;

    float* Qall = (float*)d_ws;                        // [4*HW][64]
    float* Kall = Qall + (size_t)4 * HW * 64;          // [4*HW][64]
    float* Qn   = Kall + (size_t)4 * HW * 64;          // [2*HW][64]
    float* Kn   = Qn + (size_t)2 * HW * 64;            // [2*HW][64]
    unsigned short* catb   = (unsigned short*)(Kn + (size_t)2 * HW * 64);  // [4*HW][512]
    unsigned short* xlo    = catb + (size_t)4 * HW * 512;   // [4*HW][256]
    unsigned short* Wqk_hi = xlo + (size_t)4 * HW * 256;    // [128][256]
    unsigned short* Wqk_lo = Wqk_hi + 128 * 256;
    unsigned short* Wvb    = Wqk_lo + 128 * 256;            // [256][512]

    prep<<<3648, 256, 0, stream>>>(x, Wq, Wk, Wv, catb, xlo, Wqk_hi, Wqk_lo, Wvb);

    // Q,K for all 4 batches (hi read from catb cols 0..255, stride 512)
    projqk<<<dim3(392, 2), 256, 0, stream>>>(Wqk_hi, Wqk_lo, catb, 512, xlo, Qall, Kall);

    // align 1: ta = x[2:4], tb = x[0:2] -> xt1 hi -> catb cols 256..; Qn/Kn via linearity
    attn_kernel<true><<<1568, 256, 0, stream>>>(Qall + (size_t)2 * HW * 64, Kall + (size_t)2 * HW * 64,
                                                Kall, catb, catb + 256,
                                                Qall, Qn, Kn);

    // align 2: ta = xt1, tb = x[2:4] -> xt2 hi -> catb cols 256.. (batches 2,3)
    attn_kernel<false><<<1568, 256, 0, stream>>>(Qn, Kn, Kall + (size_t)2 * HW * 64,
                                                 catb + (size_t)2 * HW * 512,
                                                 catb + (size_t)2 * HW * 512 + 256,
                                                 nullptr, nullptr, nullptr);

    // fused 1x1 conv (512->256) + BN + ReLU
    conv_mfma<<<dim3(196, 4), 256, 0, stream>>>(catb, Wvb, bv, gamma, beta, rmean, rvar, out);
}

// Round 6
// 77.003 us; speedup vs baseline: 1.5127x; 1.5127x over previous
//
#include <hip/hip_runtime.h>
#include <hip/hip_bf16.h>

#define HW 3136
#define W56 56

typedef __attribute__((ext_vector_type(8))) short short8;
typedef __attribute__((ext_vector_type(4))) float f32x4;

static __device__ __forceinline__ f32x4 mfma16(short8 a, short8 b, f32x4 c) {
    return __builtin_amdgcn_mfma_f32_16x16x32_bf16(a, b, c, 0, 0, 0);
}
static __device__ __forceinline__ float b2f(unsigned short u) {
    unsigned int x = ((unsigned int)u) << 16;
    return __builtin_bit_cast(float, x);
}
static __device__ __forceinline__ unsigned short f2b(float f) {
    __hip_bfloat16 h = __float2bfloat16(f);
    return *(unsigned short*)&h;
}

// ---------------- prep ----------------
// blocks 0..3135: transpose x -> catb bf16 cols 0..255 (hi) + xlo bf16 [4HW][256]
// blocks 3136..3647: weight conversion (Wqk split hi/lo, Wv plain bf16)
__global__ __launch_bounds__(256) void prep(const float* __restrict__ x,
                                            const float* __restrict__ Wq, const float* __restrict__ Wk,
                                            const float* __restrict__ Wv,
                                            unsigned short* __restrict__ catb,
                                            unsigned short* __restrict__ xlo,
                                            unsigned short* __restrict__ Wqk_hi,
                                            unsigned short* __restrict__ Wqk_lo,
                                            unsigned short* __restrict__ Wvb) {
    __shared__ float tile[32][33];
    int bx = blockIdx.x, tid = threadIdx.x;
    if (bx < 3136) {
        int b = bx / 784, rem = bx % 784;
        int p0 = (rem >> 3) * 32, c0 = (rem & 7) * 32;
        int tx = tid & 31, ty = tid >> 5;
#pragma unroll
        for (int i = ty; i < 32; i += 8)
            tile[i][tx] = x[((size_t)b * 256 + c0 + i) * HW + p0 + tx];
        __syncthreads();
#pragma unroll
        for (int i = ty; i < 32; i += 8) {
            float v = tile[tx][i];
            unsigned short hi = f2b(v);
            unsigned short lo = f2b(v - b2f(hi));
            size_t row = (size_t)b * HW + p0 + i;
            catb[row * 512 + c0 + tx] = hi;
            xlo[row * 256 + c0 + tx] = lo;
        }
    } else {
        int i = (bx - 3136) * 256 + tid;
        if (i < 32768) {
            float w = (i < 16384) ? Wq[i] : Wk[i - 16384];
            unsigned short hi = f2b(w);
            Wqk_hi[i] = hi;
            Wqk_lo[i] = f2b(w - b2f(hi));
        }
        if (i < 131072) Wvb[i] = f2b(Wv[i]);
    }
}

// ---------------- projqk: 64 W-rows x px(32), K=256, split-bf16 (3 MFMA products) ----------------
// grid.x = npx/32, grid.y = 2 (y=0 -> Q rows 0..63, y=1 -> K rows 64..127).
__global__ __launch_bounds__(256) void projqk(const unsigned short* __restrict__ Whi,
                                              const unsigned short* __restrict__ Wlo,
                                              const unsigned short* __restrict__ Bhi_g, int bstr,
                                              const unsigned short* __restrict__ Blo_g,
                                              float* __restrict__ Qout, float* __restrict__ Kout) {
    __shared__ short Ahi[64][72], Alo[64][72];
    __shared__ short Bhi[32][72], Blo[32][72];
    int tid = threadIdx.x, lane = tid & 63, wv = tid >> 6;
    int l15 = lane & 15, lk = (lane >> 4) * 8;
    int pxb = blockIdx.x * 32;
    int y64 = blockIdx.y * 64;
    f32x4 acc[2];
    acc[0] = (f32x4){0.f, 0.f, 0.f, 0.f};
    acc[1] = (f32x4){0.f, 0.f, 0.f, 0.f};

    for (int kt = 0; kt < 256; kt += 64) {
#pragma unroll
        for (int s = 0; s < 2; ++s) {
            int q = tid + 256 * s;
            int r = q >> 3, c = (q & 7) * 8;
            *(short8*)&Ahi[r][c] = *(const short8*)(Whi + (size_t)(y64 + r) * 256 + kt + c);
            *(short8*)&Alo[r][c] = *(const short8*)(Wlo + (size_t)(y64 + r) * 256 + kt + c);
        }
        {
            int r = tid >> 3, c = (tid & 7) * 8;
            *(short8*)&Bhi[r][c] = *(const short8*)(Bhi_g + (size_t)(pxb + r) * bstr + kt + c);
            *(short8*)&Blo[r][c] = *(const short8*)(Blo_g + (size_t)(pxb + r) * 256 + kt + c);
        }
        __syncthreads();
#pragma unroll
        for (int ks = 0; ks < 2; ++ks) {
            short8 ah = *(const short8*)&Ahi[wv * 16 + l15][ks * 32 + lk];
            short8 al = *(const short8*)&Alo[wv * 16 + l15][ks * 32 + lk];
            short8 bh[2], bl[2];
#pragma unroll
            for (int j = 0; j < 2; ++j) {
                bh[j] = *(const short8*)&Bhi[j * 16 + l15][ks * 32 + lk];
                bl[j] = *(const short8*)&Blo[j * 16 + l15][ks * 32 + lk];
            }
#pragma unroll
            for (int j = 0; j < 2; ++j) {
                acc[j] = mfma16(ah, bh[j], acc[j]);
                acc[j] = mfma16(ah, bl[j], acc[j]);
                acc[j] = mfma16(al, bh[j], acc[j]);
            }
        }
        __syncthreads();
    }
    int d0 = wv * 16 + (lane >> 4) * 4;
    float* base = blockIdx.y ? Kout : Qout;
#pragma unroll
    for (int j = 0; j < 2; ++j) {
        int px = pxb + j * 16 + l15;
        *(f32x4*)(base + (size_t)px * 64 + d0) = acc[j];
    }
}

// ---------------- attention: one wave per output pixel ----------------
// PV phase restructured for memory-level parallelism: wave splits into two row-halves
// (lanes 0..31 accumulate key-rows 0..24, lanes 32..63 rows 25..49), each lane owns
// 8 channels via 16B short8 loads, 12 gathers in flight; __shfl_xor(32) combines halves.
__global__ __launch_bounds__(256) void attn_kernel(const float* __restrict__ Q, const float* __restrict__ Kself,
                                                   const float* __restrict__ Kb,
                                                   const unsigned short* __restrict__ V,
                                                   unsigned short* __restrict__ outb,
                                                   unsigned short* __restrict__ outlo) {
    __shared__ float qs[4][64];
    __shared__ float wsh[4][64];
    __shared__ int njsh[4][64];
    int tid = threadIdx.x, lane = tid & 63, wv = tid >> 6;
    int nbc = gridDim.x >> 3;  // blocks per XCD chunk (1568/8 = 196)
    int lb = (blockIdx.x & 7) * nbc + (blockIdx.x >> 3);
    int gw = lb * 4 + wv;
    int b = gw / HW, pix = gw % HW;
    int py = pix / W56, px = pix % W56;
    qs[wv][lane] = Q[(size_t)gw * 64 + lane];
    __syncthreads();

    float logit = 0.f;
    int valid = 0, nj = 0;
    if (lane == 0) {
        valid = 1;
    } else if (lane < 50) {
        int d = lane - 1, dy = d / 7 - 3, dx = d % 7 - 3;
        int ny = py + dy, nx = px + dx;
        if (ny >= 0 && ny < W56 && nx >= 0 && nx < W56) { valid = 1; nj = ny * W56 + nx; }
    }
    if (lane < 50 && valid) {
        const float4* k4 = (lane == 0) ? (const float4*)(Kself + (size_t)gw * 64)
                                       : (const float4*)(Kb + ((size_t)b * HW + nj) * 64);
        const float4* q4 = (const float4*)qs[wv];
        float acc = 0.f;
#pragma unroll
        for (int i = 0; i < 16; ++i) {
            float4 kv = k4[i], qv = q4[i];
            acc += kv.x * qv.x + kv.y * qv.y + kv.z * qv.z + kv.w * qv.w;
        }
        logit = acc;
    }
    // zero-padded (OOB) neighbors: logit exactly 0, in denominator (matches reference)
    float m = (lane < 50) ? logit : -1e30f;
#pragma unroll
    for (int off = 32; off; off >>= 1) m = fmaxf(m, __shfl_xor(m, off));
    float e = (lane < 50) ? __expf(logit - m) : 0.f;
    float s = e;
#pragma unroll
    for (int off = 32; off; off >>= 1) s += __shfl_xor(s, off);
    // self column (lane 0) dropped; OOB & pad lanes weight 0, nj 0 -> branchless V loop is exact
    float w = (lane >= 1 && lane < 50 && valid) ? e / s : 0.f;
    wsh[wv][lane] = w;
    njsh[wv][lane] = nj;
    __syncthreads();

    // PV: half-row split, 8 channels/lane, 12 loads in flight
    int h = lane >> 5, l32 = lane & 31;
    int jb = h * 25;  // h=0: rows 0..24, h=1: rows 25..49 (row 0 has w=0)
    float av[8];
#pragma unroll
    for (int c = 0; c < 8; ++c) av[c] = 0.f;
    const unsigned short* vb = V + (size_t)b * HW * 512 + l32 * 8;
#pragma unroll
    for (int g = 0; g < 2; ++g) {
        float wj[12];
        short8 vj[12];
#pragma unroll
        for (int u = 0; u < 12; ++u) {
            int j = jb + g * 12 + u;
            wj[u] = wsh[wv][j];
            vj[u] = *(const short8*)(vb + (size_t)njsh[wv][j] * 512);
        }
#pragma unroll
        for (int u = 0; u < 12; ++u)
#pragma unroll
            for (int c = 0; c < 8; ++c)
                av[c] += wj[u] * b2f((unsigned short)vj[u][c]);
    }
    {   // tail row j = jb + 24
        int j = jb + 24;
        float wt = wsh[wv][j];
        short8 vt = *(const short8*)(vb + (size_t)njsh[wv][j] * 512);
#pragma unroll
        for (int c = 0; c < 8; ++c) av[c] += wt * b2f((unsigned short)vt[c]);
    }
#pragma unroll
    for (int c = 0; c < 8; ++c) av[c] += __shfl_xor(av[c], 32);

    if (h == 0) {
        short8 pk, lo8;
#pragma unroll
        for (int c = 0; c < 8; ++c) {
            unsigned short hi = f2b(av[c]);
            pk[c] = (short)hi;
            lo8[c] = (short)f2b(av[c] - b2f(hi));
        }
        *(short8*)(outb + (size_t)gw * 512 + l32 * 8) = pk;
        if (outlo) *(short8*)(outlo + (size_t)gw * 256 + l32 * 8) = lo8;
    }
}

// ---------------- conv (512->256) via MFMA + BN + ReLU ----------------
__global__ __launch_bounds__(256) void conv_mfma(const unsigned short* __restrict__ catb,
                                                 const unsigned short* __restrict__ Wvb,
                                                 const float* __restrict__ bv, const float* __restrict__ gamma,
                                                 const float* __restrict__ beta, const float* __restrict__ rmean,
                                                 const float* __restrict__ rvar, float* __restrict__ out) {
    __shared__ short Ald[64][72];
    __shared__ short Bld[64][72];
    int tid = threadIdx.x, lane = tid & 63, wv = tid >> 6;
    int wm = wv >> 1, wn = wv & 1;
    int l15 = lane & 15, lk = (lane >> 4) * 8;
    int n0g = blockIdx.x * 64;
    int m0g = blockIdx.y * 64;
    f32x4 acc[2][2];
#pragma unroll
    for (int i = 0; i < 2; ++i)
#pragma unroll
        for (int j = 0; j < 2; ++j) acc[i][j] = (f32x4){0.f, 0.f, 0.f, 0.f};

    float sc_[2][4], sh_[2][4];
#pragma unroll
    for (int i = 0; i < 2; ++i) {
        int ob = m0g + wm * 32 + i * 16 + (lane >> 4) * 4;
#pragma unroll
        for (int r = 0; r < 4; ++r) {
            int o = ob + r;
            float s = gamma[o] * rsqrtf(rvar[o] + 1e-5f);
            sc_[i][r] = s;
            sh_[i][r] = (bv[o] - rmean[o]) * s + beta[o];
        }
    }

    for (int kt = 0; kt < 512; kt += 64) {
#pragma unroll
        for (int s = 0; s < 2; ++s) {
            int q = tid + 256 * s;
            int r = q >> 3, c = (q & 7) * 8;
            *(short8*)&Ald[r][c] = *(const short8*)(Wvb + (size_t)(m0g + r) * 512 + kt + c);
            *(short8*)&Bld[r][c] = *(const short8*)(catb + (size_t)(n0g + r) * 512 + kt + c);
        }
        __syncthreads();
#pragma unroll
        for (int ks = 0; ks < 2; ++ks) {
            short8 a[2], b[2];
#pragma unroll
            for (int i = 0; i < 2; ++i) a[i] = *(const short8*)&Ald[wm * 32 + i * 16 + l15][ks * 32 + lk];
#pragma unroll
            for (int j = 0; j < 2; ++j) b[j] = *(const short8*)&Bld[wn * 32 + j * 16 + l15][ks * 32 + lk];
#pragma unroll
            for (int i = 0; i < 2; ++i)
#pragma unroll
                for (int j = 0; j < 2; ++j) acc[i][j] = mfma16(a[i], b[j], acc[i][j]);
        }
        __syncthreads();
    }
#pragma unroll
    for (int i = 0; i < 2; ++i) {
        int ob = m0g + wm * 32 + i * 16 + (lane >> 4) * 4;
#pragma unroll
        for (int j = 0; j < 2; ++j) {
            int px = n0g + wn * 32 + j * 16 + l15;
            int b = px / HW, p = px - b * HW;
            f32x4 v = acc[i][j];
#pragma unroll
            for (int r = 0; r < 4; ++r) {
                out[((size_t)(b * 256 + ob + r)) * HW + p] = fmaxf(v[r] * sc_[i][r] + sh_[i][r], 0.f);
            }
        }
    }
}

extern "C" void kernel_launch(void* const* d_in, const int* in_sizes, int n_in,
                              void* d_out, int out_size, void* d_ws, size_t ws_size,
                              hipStream_t stream) {
    const float* x     = (const float*)d_in[0];
    const float* Wq    = (const float*)d_in[1];
    const float* Wk    = (const float*)d_in[2];
    const float* Wv    = (const float*)d_in[3];
    const float* bv    = (const float*)d_in[4];
    const float* gamma = (const float*)d_in[5];
    const float* beta  = (const float*)d_in[6];
    const float* rmean = (const float*)d_in[7];
    const float* rvar  = (const float*)d_in[8];
    float* out = (float*)d_out;

    float* Qall = (float*)d_ws;                        // [4*HW][64]
    float* Kall = Qall + (size_t)4 * HW * 64;          // [4*HW][64]
    float* Qn   = Kall + (size_t)4 * HW * 64;          // [2*HW][64]
    float* Kn   = Qn + (size_t)2 * HW * 64;            // [2*HW][64]
    unsigned short* catb   = (unsigned short*)(Kn + (size_t)2 * HW * 64);  // [4*HW][512]
    unsigned short* xlo    = catb + (size_t)4 * HW * 512;   // [4*HW][256]
    unsigned short* xt1lo  = xlo + (size_t)4 * HW * 256;    // [2*HW][256]
    unsigned short* Wqk_hi = xt1lo + (size_t)2 * HW * 256;  // [128][256]
    unsigned short* Wqk_lo = Wqk_hi + 128 * 256;
    unsigned short* Wvb    = Wqk_lo + 128 * 256;            // [256][512]

    prep<<<3648, 256, 0, stream>>>(x, Wq, Wk, Wv, catb, xlo, Wqk_hi, Wqk_lo, Wvb);

    // Q,K for all 4 batches (hi read from catb cols 0..255, stride 512)
    projqk<<<dim3(392, 2), 256, 0, stream>>>(Wqk_hi, Wqk_lo, catb, 512, xlo, Qall, Kall);

    // align 1: ta = x[2:4], tb = x[0:2] -> xt1 (hi -> catb cols 256.., lo -> xt1lo)
    attn_kernel<<<1568, 256, 0, stream>>>(Qall + (size_t)2 * HW * 64, Kall + (size_t)2 * HW * 64,
                                          Kall, catb, catb + 256, xt1lo);

    // Q,K of xt1 (hi from catb cols 256..511 of batches 0..1, lo from xt1lo)
    projqk<<<dim3(196, 2), 256, 0, stream>>>(Wqk_hi, Wqk_lo, catb + 256, 512, xt1lo, Qn, Kn);

    // align 2: ta = xt1, tb = x[2:4] -> xt2
    attn_kernel<<<1568, 256, 0, stream>>>(Qn, Kn, Kall + (size_t)2 * HW * 64,
                                          catb + (size_t)2 * HW * 512,
                                          catb + (size_t)2 * HW * 512 + 256, nullptr);

    // fused 1x1 conv (512->256) + BN + ReLU
    conv_mfma<<<dim3(196, 4), 256, 0, stream>>>(catb, Wvb, bv, gamma, beta, rmean, rvar, out);
}

// Round 7
// 65.398 us; speedup vs baseline: 1.7811x; 1.1775x over previous
//
#include <hip/hip_runtime.h>
#include <hip/hip_bf16.h>

#define HW 3136
#define W56 56

typedef __attribute__((ext_vector_type(8))) short short8;
typedef __attribute__((ext_vector_type(4))) float f32x4;

static __device__ __forceinline__ f32x4 mfma16(short8 a, short8 b, f32x4 c) {
    return __builtin_amdgcn_mfma_f32_16x16x32_bf16(a, b, c, 0, 0, 0);
}
static __device__ __forceinline__ float b2f(unsigned short u) {
    unsigned int x = ((unsigned int)u) << 16;
    return __builtin_bit_cast(float, x);
}
static __device__ __forceinline__ unsigned short f2b(float f) {
    __hip_bfloat16 h = __float2bfloat16(f);
    return *(unsigned short*)&h;
}

// ---------------- prep ----------------
// blocks 0..3135: transpose x -> catb bf16 cols 0..255 (hi) + xlo bf16 [4HW][256]
// blocks 3136..3647: weight conversion (Wqk split hi/lo, Wv plain bf16)
__global__ __launch_bounds__(256) void prep(const float* __restrict__ x,
                                            const float* __restrict__ Wq, const float* __restrict__ Wk,
                                            const float* __restrict__ Wv,
                                            unsigned short* __restrict__ catb,
                                            unsigned short* __restrict__ xlo,
                                            unsigned short* __restrict__ Wqk_hi,
                                            unsigned short* __restrict__ Wqk_lo,
                                            unsigned short* __restrict__ Wvb) {
    __shared__ float tile[32][33];
    int bx = blockIdx.x, tid = threadIdx.x;
    if (bx < 3136) {
        int b = bx / 784, rem = bx % 784;
        int p0 = (rem >> 3) * 32, c0 = (rem & 7) * 32;
        int tx = tid & 31, ty = tid >> 5;
#pragma unroll
        for (int i = ty; i < 32; i += 8)
            tile[i][tx] = x[((size_t)b * 256 + c0 + i) * HW + p0 + tx];
        __syncthreads();
#pragma unroll
        for (int i = ty; i < 32; i += 8) {
            float v = tile[tx][i];
            unsigned short hi = f2b(v);
            unsigned short lo = f2b(v - b2f(hi));
            size_t row = (size_t)b * HW + p0 + i;
            catb[row * 512 + c0 + tx] = hi;
            xlo[row * 256 + c0 + tx] = lo;
        }
    } else {
        int i = (bx - 3136) * 256 + tid;
        if (i < 32768) {
            float w = (i < 16384) ? Wq[i] : Wk[i - 16384];
            unsigned short hi = f2b(w);
            Wqk_hi[i] = hi;
            Wqk_lo[i] = f2b(w - b2f(hi));
        }
        if (i < 131072) Wvb[i] = f2b(Wv[i]);
    }
}

// ---------------- projqk: 64 W-rows x px(32), K=256, split-bf16 (3 MFMA products) ----------------
// grid.x = npx/32, grid.y = 2 (y=0 -> Q rows 0..63, y=1 -> K rows 64..127).
__global__ __launch_bounds__(256) void projqk(const unsigned short* __restrict__ Whi,
                                              const unsigned short* __restrict__ Wlo,
                                              const unsigned short* __restrict__ Bhi_g, int bstr,
                                              const unsigned short* __restrict__ Blo_g,
                                              float* __restrict__ Qout, float* __restrict__ Kout) {
    __shared__ short Ahi[64][72], Alo[64][72];
    __shared__ short Bhi[32][72], Blo[32][72];
    int tid = threadIdx.x, lane = tid & 63, wv = tid >> 6;
    int l15 = lane & 15, lk = (lane >> 4) * 8;
    int pxb = blockIdx.x * 32;
    int y64 = blockIdx.y * 64;
    f32x4 acc[2];
    acc[0] = (f32x4){0.f, 0.f, 0.f, 0.f};
    acc[1] = (f32x4){0.f, 0.f, 0.f, 0.f};

    for (int kt = 0; kt < 256; kt += 64) {
#pragma unroll
        for (int s = 0; s < 2; ++s) {
            int q = tid + 256 * s;
            int r = q >> 3, c = (q & 7) * 8;
            *(short8*)&Ahi[r][c] = *(const short8*)(Whi + (size_t)(y64 + r) * 256 + kt + c);
            *(short8*)&Alo[r][c] = *(const short8*)(Wlo + (size_t)(y64 + r) * 256 + kt + c);
        }
        {
            int r = tid >> 3, c = (tid & 7) * 8;
            *(short8*)&Bhi[r][c] = *(const short8*)(Bhi_g + (size_t)(pxb + r) * bstr + kt + c);
            *(short8*)&Blo[r][c] = *(const short8*)(Blo_g + (size_t)(pxb + r) * 256 + kt + c);
        }
        __syncthreads();
#pragma unroll
        for (int ks = 0; ks < 2; ++ks) {
            short8 ah = *(const short8*)&Ahi[wv * 16 + l15][ks * 32 + lk];
            short8 al = *(const short8*)&Alo[wv * 16 + l15][ks * 32 + lk];
            short8 bh[2], bl[2];
#pragma unroll
            for (int j = 0; j < 2; ++j) {
                bh[j] = *(const short8*)&Bhi[j * 16 + l15][ks * 32 + lk];
                bl[j] = *(const short8*)&Blo[j * 16 + l15][ks * 32 + lk];
            }
#pragma unroll
            for (int j = 0; j < 2; ++j) {
                acc[j] = mfma16(ah, bh[j], acc[j]);
                acc[j] = mfma16(ah, bl[j], acc[j]);
                acc[j] = mfma16(al, bh[j], acc[j]);
            }
        }
        __syncthreads();
    }
    int d0 = wv * 16 + (lane >> 4) * 4;
    float* base = blockIdx.y ? Kout : Qout;
#pragma unroll
    for (int j = 0; j < 2; ++j) {
        int px = pxb + j * 16 + l15;
        *(f32x4*)(base + (size_t)px * 64 + d0) = acc[j];
    }
}

// ---------------- attention: one wave per output pixel ----------------
// QK phase: coalesced-transposed gather. lane = (rg = row-group 0..3, c = chunk 0..15);
// instruction i loads rows {4i+rg} chunk c (16B) -> 4 rows x 256B contiguous per instr
// (~210 cache lines/wave vs ~800 for row-per-lane), 13 loads in flight. Dot finished by
// 4-step shfl_xor butterfly over chunk lanes; logits scattered via per-wave LDS.
// Self-key unified: K rows addressed as Kbase[selfOff+gw] / Kbase[kbOff + b*HW+nj].
// PV phase: half-row split, 8 channels/lane, 12 gathers in flight; shfl_xor(32) combine.
__global__ __launch_bounds__(256) void attn_kernel(const float* __restrict__ Q,
                                                   const float* __restrict__ Kbase,
                                                   int selfOff, int kbOff,
                                                   const unsigned short* __restrict__ V,
                                                   unsigned short* __restrict__ outb,
                                                   unsigned short* __restrict__ outlo) {
    __shared__ float qs[4][64];
    __shared__ float wsh[4][64];
    __shared__ float ls[4][52];
    __shared__ int njsh[4][64];
    int tid = threadIdx.x, lane = tid & 63, wv = tid >> 6;
    int nbc = gridDim.x >> 3;  // blocks per XCD chunk (1568/8 = 196)
    int lb = (blockIdx.x & 7) * nbc + (blockIdx.x >> 3);
    int gw = lb * 4 + wv;
    int b = gw / HW, pix = gw % HW;
    int py = pix / W56, px = pix % W56;
    qs[wv][lane] = Q[(size_t)gw * 64 + lane];

    int valid = 0, nj = 0;
    if (lane == 0) {
        valid = 1;
    } else if (lane < 50) {
        int d = lane - 1, dy = d / 7 - 3, dx = d % 7 - 3;
        int ny = py + dy, nx = px + dx;
        if (ny >= 0 && ny < W56 && nx >= 0 && nx < W56) { valid = 1; nj = ny * W56 + nx; }
    }
    njsh[wv][lane] = nj;
    unsigned long long vmask = __ballot(lane < 50 && valid);
    __syncthreads();

    // ---- QK logits, coalesced-transposed ----
    int rg = lane >> 4, c = lane & 15;
    f32x4 qf = *(const f32x4*)&qs[wv][c * 4];
    float4 kvv[13];
#pragma unroll
    for (int i = 0; i < 13; ++i) {
        int r = i * 4 + rg;
        int row = (i == 0 && rg == 0) ? (selfOff + gw) : (kbOff + b * HW + njsh[wv][r]);
        kvv[i] = *(const float4*)(Kbase + (size_t)row * 64 + c * 4);
    }
    float pl[13];
#pragma unroll
    for (int i = 0; i < 13; ++i)
        pl[i] = kvv[i].x * qf[0] + kvv[i].y * qf[1] + kvv[i].z * qf[2] + kvv[i].w * qf[3];
#pragma unroll
    for (int off = 1; off < 16; off <<= 1)
#pragma unroll
        for (int i = 0; i < 13; ++i) pl[i] += __shfl_xor(pl[i], off);
    // scatter logits to per-wave LDS: lane (rg,c) writes row c*4+rg with pl[c]
    float myl = 0.f;
#pragma unroll
    for (int i = 0; i < 13; ++i) myl = (c == i) ? pl[i] : myl;
    if (c < 13) ls[wv][c * 4 + rg] = myl;

    // ---- softmax (per-row values back on lanes 0..49) ----
    bool ok = (lane == 0) || (lane < 50 && ((vmask >> lane) & 1ull));
    float logit = (lane < 50 && ok) ? ls[wv][lane] : 0.f;
    // zero-padded (OOB) neighbors: logit exactly 0, in denominator (matches reference)
    float m = (lane < 50) ? logit : -1e30f;
#pragma unroll
    for (int off = 32; off; off >>= 1) m = fmaxf(m, __shfl_xor(m, off));
    float e = (lane < 50) ? __expf(logit - m) : 0.f;
    float s = e;
#pragma unroll
    for (int off = 32; off; off >>= 1) s += __shfl_xor(s, off);
    // self column (lane 0) dropped; OOB & pad lanes weight 0, nj 0 -> branchless V loop is exact
    float w = (lane >= 1 && lane < 50 && valid) ? e / s : 0.f;
    wsh[wv][lane] = w;
    __syncthreads();

    // ---- PV: half-row split, 8 channels/lane, 12 loads in flight ----
    int h = lane >> 5, l32 = lane & 31;
    int jb = h * 25;  // h=0: rows 0..24, h=1: rows 25..49 (row 0 has w=0)
    float av[8];
#pragma unroll
    for (int cc = 0; cc < 8; ++cc) av[cc] = 0.f;
    const unsigned short* vb = V + (size_t)b * HW * 512 + l32 * 8;
#pragma unroll
    for (int g = 0; g < 2; ++g) {
        float wj[12];
        short8 vj[12];
#pragma unroll
        for (int u = 0; u < 12; ++u) {
            int j = jb + g * 12 + u;
            wj[u] = wsh[wv][j];
            vj[u] = *(const short8*)(vb + (size_t)njsh[wv][j] * 512);
        }
#pragma unroll
        for (int u = 0; u < 12; ++u)
#pragma unroll
            for (int cc = 0; cc < 8; ++cc)
                av[cc] += wj[u] * b2f((unsigned short)vj[u][cc]);
    }
    {   // tail row j = jb + 24
        int j = jb + 24;
        float wt = wsh[wv][j];
        short8 vt = *(const short8*)(vb + (size_t)njsh[wv][j] * 512);
#pragma unroll
        for (int cc = 0; cc < 8; ++cc) av[cc] += wt * b2f((unsigned short)vt[cc]);
    }
#pragma unroll
    for (int cc = 0; cc < 8; ++cc) av[cc] += __shfl_xor(av[cc], 32);

    if (h == 0) {
        short8 pk, lo8;
#pragma unroll
        for (int cc = 0; cc < 8; ++cc) {
            unsigned short hi = f2b(av[cc]);
            pk[cc] = (short)hi;
            lo8[cc] = (short)f2b(av[cc] - b2f(hi));
        }
        *(short8*)(outb + (size_t)gw * 512 + l32 * 8) = pk;
        if (outlo) *(short8*)(outlo + (size_t)gw * 256 + l32 * 8) = lo8;
    }
}

// ---------------- conv (512->256) via MFMA + BN + ReLU ----------------
__global__ __launch_bounds__(256) void conv_mfma(const unsigned short* __restrict__ catb,
                                                 const unsigned short* __restrict__ Wvb,
                                                 const float* __restrict__ bv, const float* __restrict__ gamma,
                                                 const float* __restrict__ beta, const float* __restrict__ rmean,
                                                 const float* __restrict__ rvar, float* __restrict__ out) {
    __shared__ short Ald[64][72];
    __shared__ short Bld[64][72];
    int tid = threadIdx.x, lane = tid & 63, wv = tid >> 6;
    int wm = wv >> 1, wn = wv & 1;
    int l15 = lane & 15, lk = (lane >> 4) * 8;
    int n0g = blockIdx.x * 64;
    int m0g = blockIdx.y * 64;
    f32x4 acc[2][2];
#pragma unroll
    for (int i = 0; i < 2; ++i)
#pragma unroll
        for (int j = 0; j < 2; ++j) acc[i][j] = (f32x4){0.f, 0.f, 0.f, 0.f};

    float sc_[2][4], sh_[2][4];
#pragma unroll
    for (int i = 0; i < 2; ++i) {
        int ob = m0g + wm * 32 + i * 16 + (lane >> 4) * 4;
#pragma unroll
        for (int r = 0; r < 4; ++r) {
            int o = ob + r;
            float s = gamma[o] * rsqrtf(rvar[o] + 1e-5f);
            sc_[i][r] = s;
            sh_[i][r] = (bv[o] - rmean[o]) * s + beta[o];
        }
    }

    for (int kt = 0; kt < 512; kt += 64) {
#pragma unroll
        for (int s = 0; s < 2; ++s) {
            int q = tid + 256 * s;
            int r = q >> 3, c = (q & 7) * 8;
            *(short8*)&Ald[r][c] = *(const short8*)(Wvb + (size_t)(m0g + r) * 512 + kt + c);
            *(short8*)&Bld[r][c] = *(const short8*)(catb + (size_t)(n0g + r) * 512 + kt + c);
        }
        __syncthreads();
#pragma unroll
        for (int ks = 0; ks < 2; ++ks) {
            short8 a[2], b[2];
#pragma unroll
            for (int i = 0; i < 2; ++i) a[i] = *(const short8*)&Ald[wm * 32 + i * 16 + l15][ks * 32 + lk];
#pragma unroll
            for (int j = 0; j < 2; ++j) b[j] = *(const short8*)&Bld[wn * 32 + j * 16 + l15][ks * 32 + lk];
#pragma unroll
            for (int i = 0; i < 2; ++i)
#pragma unroll
                for (int j = 0; j < 2; ++j) acc[i][j] = mfma16(a[i], b[j], acc[i][j]);
        }
        __syncthreads();
    }
#pragma unroll
    for (int i = 0; i < 2; ++i) {
        int ob = m0g + wm * 32 + i * 16 + (lane >> 4) * 4;
#pragma unroll
        for (int j = 0; j < 2; ++j) {
            int px = n0g + wn * 32 + j * 16 + l15;
            int b = px / HW, p = px - b * HW;
            f32x4 v = acc[i][j];
#pragma unroll
            for (int r = 0; r < 4; ++r) {
                out[((size_t)(b * 256 + ob + r)) * HW + p] = fmaxf(v[r] * sc_[i][r] + sh_[i][r], 0.f);
            }
        }
    }
}

extern "C" void kernel_launch(void* const* d_in, const int* in_sizes, int n_in,
                              void* d_out, int out_size, void* d_ws, size_t ws_size,
                              hipStream_t stream) {
    const float* x     = (const float*)d_in[0];
    const float* Wq    = (const float*)d_in[1];
    const float* Wk    = (const float*)d_in[2];
    const float* Wv    = (const float*)d_in[3];
    const float* bv    = (const float*)d_in[4];
    const float* gamma = (const float*)d_in[5];
    const float* beta  = (const float*)d_in[6];
    const float* rmean = (const float*)d_in[7];
    const float* rvar  = (const float*)d_in[8];
    float* out = (float*)d_out;

    float* Qall = (float*)d_ws;                        // [4*HW][64]
    float* Kall = Qall + (size_t)4 * HW * 64;          // [4*HW][64]  (rows 0..4HW)
    float* Qn   = Kall + (size_t)4 * HW * 64;          // [2*HW][64]  (= Kall rows 4HW..6HW)
    float* Kn   = Qn + (size_t)2 * HW * 64;            // [2*HW][64]  (= Kall rows 6HW..8HW)
    unsigned short* catb   = (unsigned short*)(Kn + (size_t)2 * HW * 64);  // [4*HW][512]
    unsigned short* xlo    = catb + (size_t)4 * HW * 512;   // [4*HW][256]
    unsigned short* xt1lo  = xlo + (size_t)4 * HW * 256;    // [2*HW][256]
    unsigned short* Wqk_hi = xt1lo + (size_t)2 * HW * 256;  // [128][256]
    unsigned short* Wqk_lo = Wqk_hi + 128 * 256;
    unsigned short* Wvb    = Wqk_lo + 128 * 256;            // [256][512]

    prep<<<3648, 256, 0, stream>>>(x, Wq, Wk, Wv, catb, xlo, Wqk_hi, Wqk_lo, Wvb);

    // Q,K for all 4 batches (hi read from catb cols 0..255, stride 512)
    projqk<<<dim3(392, 2), 256, 0, stream>>>(Wqk_hi, Wqk_lo, catb, 512, xlo, Qall, Kall);

    // align 1: ta = x[2:4], tb = x[0:2] -> xt1 (hi -> catb cols 256.., lo -> xt1lo)
    // Kself = Kall rows 2HW.. (batches 2,3); Kb = Kall rows 0.. (batches 0,1)
    attn_kernel<<<1568, 256, 0, stream>>>(Qall + (size_t)2 * HW * 64, Kall,
                                          /*selfOff=*/2 * HW, /*kbOff=*/0,
                                          catb, catb + 256, xt1lo);

    // Q,K of xt1 (hi from catb cols 256..511 of batches 0..1, lo from xt1lo)
    projqk<<<dim3(196, 2), 256, 0, stream>>>(Wqk_hi, Wqk_lo, catb + 256, 512, xt1lo, Qn, Kn);

    // align 2: ta = xt1, tb = x[2:4] -> xt2
    // Kself = Kn (= Kall rows 6HW..); Kb = Kall rows 2HW.. (batches 2,3)
    attn_kernel<<<1568, 256, 0, stream>>>(Qn, Kall,
                                          /*selfOff=*/6 * HW, /*kbOff=*/2 * HW,
                                          catb + (size_t)2 * HW * 512,
                                          catb + (size_t)2 * HW * 512 + 256, nullptr);

    // fused 1x1 conv (512->256) + BN + ReLU
    conv_mfma<<<dim3(196, 4), 256, 0, stream>>>(catb, Wvb, bv, gamma, beta, rmean, rvar, out);
}